// Round 2
// baseline (564.398 us; speedup 1.0000x reference)
//
#include <hip/hip_runtime.h>

#define BB 128
#define SS 64
#define KK 10
#define DD 256
#define NN (BB*SS)        // 8192 rows
#define ROWS 32           // rows per block
#define NBLK (NN/ROWS)    // 256 blocks = 1 per CU
#define NT 1024           // 16 waves per block -> 4 waves/SIMD

typedef __attribute__((ext_vector_type(8))) short short8;
typedef __attribute__((ext_vector_type(4))) float f32x4;

#define FRAG_ELEMS (48*8*64*8)   // 196608 bf16 values per weight matrix

__device__ __forceinline__ unsigned short f2bf(float f){
  union { float f; unsigned u; } v; v.f = f;
  unsigned r = (v.u + 0x7FFFu + ((v.u >> 16) & 1u)) >> 16;
  return (unsigned short)r;
}

// Pre-swizzle W_ih[:, :D] and W_hh into bf16 MFMA B-fragment order:
// frag value at (tn, tk, lane, j) = W[c = tn*16 + (lane&15)][d = tk*32 + (lane>>4)*8 + j]
// stored flat at ((tn*8+tk)*64 + lane)*8 + j.  FW1 first, FWhh second.
__global__ void prep_weights(const float* __restrict__ Wih,
                             const float* __restrict__ Whh,
                             unsigned short* __restrict__ fw){
  int id = blockIdx.x * 256 + threadIdx.x;     // 0 .. 2*FRAG_ELEMS-1
  int arr = (id >= FRAG_ELEMS);
  int r = arr ? (id - FRAG_ELEMS) : id;
  int j  = r & 7;
  int l  = (r >> 3) & 63;
  int tk = (r >> 9) & 7;
  int tn = r >> 12;                            // 0..47
  int c  = tn * 16 + (l & 15);                 // 0..767
  int d  = tk * 32 + ((l >> 4) << 3) + j;      // 0..255
  float v = arr ? Whh[c * 256 + d] : Wih[c * 512 + d];
  fw[id] = f2bf(v);
}

__global__ __launch_bounds__(NT, 4) void gru_main(
    const float* __restrict__ item, const float* __restrict__ user,
    const float* __restrict__ b_ih, const float* __restrict__ b_hh,
    const float* __restrict__ w_out, const float* __restrict__ b_out,
    const int* __restrict__ length, const unsigned short* __restrict__ ws,
    float* __restrict__ out)
{
  // A-fragment layout: elem (mt, tk, lane, j) at ((mt*8+tk)*64+lane)*8+j
  // double-buffered so one barrier/step suffices
  __shared__ unsigned short xfrag[2][2*8*64*8];   // 32 KB
  __shared__ unsigned short hfrag[2][2*8*64*8];   // 32 KB
  __shared__ float yp[3][16][2][4][4];            // 6 KB, triple-buffered

  const int tid  = threadIdx.x;
  const int lane = tid & 63;
  const int w    = tid >> 6;        // wave 0..15 == column group g
  const int col  = lane & 15;       // C-layout col
  const int q    = lane >> 4;       // quad
  const int nb   = blockIdx.x * ROWS;
  const int b    = nb / SS;         // one user per block (32 | 64)
  const int sk   = blockIdx.x & 7;  // tk read-order skew: decorrelate L2 same-line bursts

  const short8* fw1 = (const short8*)ws;
  const short8* fwh = fw1 + (FRAG_ELEMS/8);

  // per-column constants (this thread owns output channel d for 8 rows)
  const int d    = w*16 + col;
  const float br_  = b_ih[d]       + b_hh[d];
  const float bz_  = b_ih[256 + d] + b_hh[256 + d];
  const float bin_ = b_ih[512 + d];
  const float bhn_ = b_hh[512 + d];
  const float wo_  = w_out[d];

  // weight fragment flat offsets (in short8 units): frag(tn,tk) = fw[tn*512 + tk*64 + lane]
  const int wq0 = (w     )*512 + lane;   // gate r
  const int wq1 = (16 + w)*512 + lane;   // gate z
  const int wq2 = (32 + w)*512 + lane;   // gate n

  // h0 = user_embs[b, clip(length[b]-1,0)]; identical for all 32 rows
  int idx = length[b] - 1; if (idx < 0) idx = 0;
  const float u0 = user[((size_t)b*SS + idx)*DD + d];
  float h[2][4];
  #pragma unroll
  for (int mt = 0; mt < 2; ++mt)
    #pragma unroll
    for (int reg = 0; reg < 4; ++reg)
      h[mt][reg] = u0;

  // write h0 into hfrag[0] (A-fragment layout), owner-thread scatter
  const int tkk = d >> 5;
  const int slb = ((d >> 3) & 3) * 16;
  const int dj  = d & 7;
  {
    unsigned short hb = f2bf(u0);
    #pragma unroll
    for (int mt = 0; mt < 2; ++mt)
      #pragma unroll
      for (int reg = 0; reg < 4; ++reg)
        hfrag[0][((mt*8 + tkk)*64 + slb + q*4 + reg)*8 + dj] = hb;
  }

  // cooperative x-tile load: thread covers row = tid>>5, 8 d's at (tid&31)*8
  const int xrow = tid >> 5;        // 0..31
  const int xo   = tid & 31;        // which 8-wide d chunk
  const int xmt  = xrow >> 4;
  const int xtk  = xo >> 2;
  const int xsl  = (xo & 3)*16 + (xrow & 15);
  {
    const float4* p = (const float4*)(item + ((size_t)(nb + xrow)*KK + 0)*DD + xo*8);
    float4 a0 = p[0], a1 = p[1];
    unsigned short t[8];
    t[0]=f2bf(a0.x); t[1]=f2bf(a0.y); t[2]=f2bf(a0.z); t[3]=f2bf(a0.w);
    t[4]=f2bf(a1.x); t[5]=f2bf(a1.y); t[6]=f2bf(a1.z); t[7]=f2bf(a1.w);
    *(short8*)&xfrag[0][((xmt*8 + xtk)*64 + xsl)*8] = *(short8*)t;
  }

  // prime the weight prefetch ring with tk-slice `sk` (issues before the barrier)
  short8 wa0,wa1,wa2,wa3,wa4,wa5, wb0,wb1,wb2,wb3,wb4,wb5;
  {
    const int o_ = sk*64;
    wa0 = fw1[wq0+o_]; wa1 = fw1[wq1+o_]; wa2 = fw1[wq2+o_];
    wa3 = fwh[wq0+o_]; wa4 = fwh[wq1+o_]; wa5 = fwh[wq2+o_];
  }

  __syncthreads();

  const float bout = b_out[0];

#define MFMA16(A,Bv,C) __builtin_amdgcn_mfma_f32_16x16x32_bf16(A,Bv,C,0,0,0)
  // One tk sub-step: consume weight slice C*, prefetch slice ((TK)+1+sk)&7 into N*.
  // At TK==7 the prefetch wraps to slice sk == next step's first slice (addresses are
  // k-invariant), so the weight-load pipe never drains across the gate phase / barrier.
#define TKSTEP(C0,C1,C2,C3,C4,C5, N0,N1,N2,N3,N4,N5, TK) do{ \
      const int tkv_ = ((TK)+sk)&7; const int o_ = (((TK)+1+sk)&7)*64; \
      N0 = fw1[wq0+o_]; N1 = fw1[wq1+o_]; N2 = fw1[wq2+o_]; \
      N3 = fwh[wq0+o_]; N4 = fwh[wq1+o_]; N5 = fwh[wq2+o_]; \
      short8 ax0 = *(const short8*)&xfrag[cb][((    tkv_)*64 + lane)*8]; \
      short8 ax1 = *(const short8*)&xfrag[cb][((8 + tkv_)*64 + lane)*8]; \
      short8 ah0 = *(const short8*)&hfrag[cb][((    tkv_)*64 + lane)*8]; \
      short8 ah1 = *(const short8*)&hfrag[cb][((8 + tkv_)*64 + lane)*8]; \
      acc[0][0] = MFMA16(ax0,C0,acc[0][0]); acc[0][0] = MFMA16(ah0,C3,acc[0][0]); \
      acc[0][1] = MFMA16(ax0,C1,acc[0][1]); acc[0][1] = MFMA16(ah0,C4,acc[0][1]); \
      acc[0][2] = MFMA16(ax0,C2,acc[0][2]); acc[0][3] = MFMA16(ah0,C5,acc[0][3]); \
      acc[1][0] = MFMA16(ax1,C0,acc[1][0]); acc[1][0] = MFMA16(ah1,C3,acc[1][0]); \
      acc[1][1] = MFMA16(ax1,C1,acc[1][1]); acc[1][1] = MFMA16(ah1,C4,acc[1][1]); \
      acc[1][2] = MFMA16(ax1,C2,acc[1][2]); acc[1][3] = MFMA16(ah1,C5,acc[1][3]); \
    }while(0)

  for (int k = 0; k < KK; ++k){
    const int cb  = k & 1;
    const int nbf = cb ^ 1;

    // accumulators: [mt][kind]  kind: 0=r 1=z 2=i_n 3=h_n
    f32x4 acc[2][4];
    #pragma unroll
    for (int mt = 0; mt < 2; ++mt)
      #pragma unroll
      for (int kd = 0; kd < 4; ++kd){
        f32x4 z4 = {0.f, 0.f, 0.f, 0.f};
        acc[mt][kd] = z4;
      }

    // next x tile issued up-front: HBM latency hides under the whole MFMA phase
    float4 xn0, xn1;
    if (k < KK-1){
      const float4* p = (const float4*)(item + ((size_t)(nb + xrow)*KK + (k+1))*DD + xo*8);
      xn0 = p[0]; xn1 = p[1];
    }

    TKSTEP(wa0,wa1,wa2,wa3,wa4,wa5, wb0,wb1,wb2,wb3,wb4,wb5, 0);
    TKSTEP(wb0,wb1,wb2,wb3,wb4,wb5, wa0,wa1,wa2,wa3,wa4,wa5, 1);
    TKSTEP(wa0,wa1,wa2,wa3,wa4,wa5, wb0,wb1,wb2,wb3,wb4,wb5, 2);
    TKSTEP(wb0,wb1,wb2,wb3,wb4,wb5, wa0,wa1,wa2,wa3,wa4,wa5, 3);
    TKSTEP(wa0,wa1,wa2,wa3,wa4,wa5, wb0,wb1,wb2,wb3,wb4,wb5, 4);
    TKSTEP(wb0,wb1,wb2,wb3,wb4,wb5, wa0,wa1,wa2,wa3,wa4,wa5, 5);
    TKSTEP(wa0,wa1,wa2,wa3,wa4,wa5, wb0,wb1,wb2,wb3,wb4,wb5, 6);
    TKSTEP(wb0,wb1,wb2,wb3,wb4,wb5, wa0,wa1,wa2,wa3,wa4,wa5, 7);

    // gates — entirely in-register; raw v_rcp (1 ulp, fine vs bf16 noise) + v_med3 clamp
    float ypl[2][4];
    #pragma unroll
    for (int mt = 0; mt < 2; ++mt)
      #pragma unroll
      for (int reg = 0; reg < 4; ++reg){
        float rp = acc[mt][0][reg] + br_;
        float zp = acc[mt][1][reg] + bz_;
        float r  = __builtin_amdgcn_rcpf(1.f + __expf(-rp));
        float z  = __builtin_amdgcn_rcpf(1.f + __expf(-zp));
        float np = acc[mt][2][reg] + bin_ + r*(acc[mt][3][reg] + bhn_);
        np = __builtin_amdgcn_fmed3f(np, -30.f, 30.f);
        float e  = __expf(2.f*np);
        float n  = 1.f - 2.f*__builtin_amdgcn_rcpf(e + 1.f);   // tanh(np)
        float hv = (1.f - z)*n + z*h[mt][reg];
        h[mt][reg] = hv;
        ypl[mt][reg] = hv * wo_;
      }

    // y partial: reduce across the 16 cols of this wave's group
    #pragma unroll
    for (int mt = 0; mt < 2; ++mt)
      #pragma unroll
      for (int reg = 0; reg < 4; ++reg){
        float p = ypl[mt][reg];
        p += __shfl_xor(p, 1);
        p += __shfl_xor(p, 2);
        p += __shfl_xor(p, 4);
        p += __shfl_xor(p, 8);
        if (col == 0) yp[k % 3][w][mt][q][reg] = p;
      }

    // write h' (bf16) into hfrag[nbf] for next step
    #pragma unroll
    for (int mt = 0; mt < 2; ++mt)
      #pragma unroll
      for (int reg = 0; reg < 4; ++reg)
        hfrag[nbf][((mt*8 + tkk)*64 + slb + q*4 + reg)*8 + dj] = f2bf(h[mt][reg]);

    // write next x tile into xfrag[nbf]
    if (k < KK-1){
      unsigned short t[8];
      t[0]=f2bf(xn0.x); t[1]=f2bf(xn0.y); t[2]=f2bf(xn0.z); t[3]=f2bf(xn0.w);
      t[4]=f2bf(xn1.x); t[5]=f2bf(xn1.y); t[6]=f2bf(xn1.z); t[7]=f2bf(xn1.w);
      *(short8*)&xfrag[nbf][((xmt*8 + xtk)*64 + xsl)*8] = *(short8*)t;
    }

    // finalize y for step k-1 (yp[(k-1)%3] stable since previous barrier;
    // concurrent writes go to yp[k%3] which is a different buffer)
    if (k > 0 && tid < 32){
      float s = bout;
      #pragma unroll
      for (int ww = 0; ww < 16; ++ww)
        s += yp[(k-1) % 3][ww][tid >> 4][(tid >> 2) & 3][tid & 3];
      out[(size_t)(nb + tid)*KK + (k-1)] = s;
    }

    __syncthreads();   // single barrier per step
  }

  // finalize y for the last step
  if (tid < 32){
    float s = bout;
    #pragma unroll
    for (int ww = 0; ww < 16; ++ww)
      s += yp[(KK-1) % 3][ww][tid >> 4][(tid >> 2) & 3][tid & 3];
    out[(size_t)(nb + tid)*KK + (KK-1)] = s;
  }
}

extern "C" void kernel_launch(void* const* d_in, const int* in_sizes, int n_in,
                              void* d_out, int out_size, void* d_ws, size_t ws_size,
                              hipStream_t stream) {
  const float* item   = (const float*)d_in[0];
  const float* user   = (const float*)d_in[1];
  const float* W_ih   = (const float*)d_in[2];
  const float* W_hh   = (const float*)d_in[3];
  const float* b_ih   = (const float*)d_in[4];
  const float* b_hh   = (const float*)d_in[5];
  const float* w_out  = (const float*)d_in[6];
  const float* b_out  = (const float*)d_in[7];
  const int*   length = (const int*)d_in[8];
  unsigned short* ws  = (unsigned short*)d_ws;   // needs 768 KB
  float* out = (float*)d_out;

  hipLaunchKernelGGL(prep_weights, dim3((2*FRAG_ELEMS)/256), dim3(256), 0, stream,
                     W_ih, W_hh, ws);
  hipLaunchKernelGGL(gru_main, dim3(NBLK), dim3(NT), 0, stream,
                     item, user, b_ih, b_hh, w_out, b_out, length, ws, out);
}

// Round 3
// 541.911 us; speedup vs baseline: 1.0415x; 1.0415x over previous
//
#include <hip/hip_runtime.h>

#define BB 128
#define SS 64
#define KK 10
#define DD 256
#define NN (BB*SS)        // 8192 rows
#define ROWS 32           // rows per block
#define NBLK (NN/ROWS)    // 256 blocks = 1 per CU
#define NT 1024           // 16 waves per block -> 4 waves/SIMD

typedef __attribute__((ext_vector_type(8))) short short8;
typedef __attribute__((ext_vector_type(4))) float f32x4;

#define FRAG_ELEMS (48*8*64*8)   // 196608 bf16 values per weight matrix

__device__ __forceinline__ unsigned short f2bf(float f){
  union { float f; unsigned u; } v; v.f = f;
  unsigned r = (v.u + 0x7FFFu + ((v.u >> 16) & 1u)) >> 16;
  return (unsigned short)r;
}

// Pre-swizzle W_ih[:, :D] and W_hh into bf16 MFMA B-fragment order:
// frag value at (tn, tk, lane, j) = W[c = tn*16 + (lane&15)][d = tk*32 + (lane>>4)*8 + j]
// stored flat at ((tn*8+tk)*64 + lane)*8 + j.  FW1 first, FWhh second.
__global__ void prep_weights(const float* __restrict__ Wih,
                             const float* __restrict__ Whh,
                             unsigned short* __restrict__ fw){
  int id = blockIdx.x * 256 + threadIdx.x;     // 0 .. 2*FRAG_ELEMS-1
  int arr = (id >= FRAG_ELEMS);
  int r = arr ? (id - FRAG_ELEMS) : id;
  int j  = r & 7;
  int l  = (r >> 3) & 63;
  int tk = (r >> 9) & 7;
  int tn = r >> 12;                            // 0..47
  int c  = tn * 16 + (l & 15);                 // 0..767
  int d  = tk * 32 + ((l >> 4) << 3) + j;      // 0..255
  float v = arr ? Whh[c * 256 + d] : Wih[c * 512 + d];
  fw[id] = f2bf(v);
}

// launch_bounds minWaves=2: backend VGPR budget = pool/2 = 128-reg cap.
// (minWaves=4 budgeted pool/4 = 64-reg cap -> the prefetch ring spilled to
//  scratch: FETCH 966MB/WRITE 282MB, 448us. HW residency is unchanged by this
//  hint: 16-wave blocks at <=128 VGPR still run 4 waves/SIMD, 1 block/CU.)
__global__ __launch_bounds__(NT, 2) void gru_main(
    const float* __restrict__ item, const float* __restrict__ user,
    const float* __restrict__ b_ih, const float* __restrict__ b_hh,
    const float* __restrict__ w_out, const float* __restrict__ b_out,
    const int* __restrict__ length, const unsigned short* __restrict__ ws,
    float* __restrict__ out)
{
  // A-fragment layout: elem (mt, tk, lane, j) at ((mt*8+tk)*64+lane)*8+j
  // double-buffered so one barrier/step suffices
  __shared__ unsigned short xfrag[2][2*8*64*8];   // 32 KB
  __shared__ unsigned short hfrag[2][2*8*64*8];   // 32 KB
  __shared__ float yp[3][16][2][4][4];            // 6 KB, triple-buffered

  const int tid  = threadIdx.x;
  const int lane = tid & 63;
  const int w    = tid >> 6;        // wave 0..15 == column group g
  const int col  = lane & 15;       // C-layout col
  const int q    = lane >> 4;       // quad
  const int nb   = blockIdx.x * ROWS;
  const int b    = nb / SS;         // one user per block (32 | 64)
  const int sk   = blockIdx.x & 7;  // tk read-order skew: decorrelate L2 same-line bursts

  const short8* fw1 = (const short8*)ws;
  const short8* fwh = fw1 + (FRAG_ELEMS/8);

  // per-column constants (this thread owns output channel d for 8 rows)
  const int d    = w*16 + col;
  const float br_  = b_ih[d]       + b_hh[d];
  const float bz_  = b_ih[256 + d] + b_hh[256 + d];
  const float bin_ = b_ih[512 + d];
  const float bhn_ = b_hh[512 + d];
  const float wo_  = w_out[d];

  // weight fragment flat offsets (in short8 units): frag(tn,tk) = fw[tn*512 + tk*64 + lane]
  const int wq0 = (w     )*512 + lane;   // gate r
  const int wq1 = (16 + w)*512 + lane;   // gate z
  const int wq2 = (32 + w)*512 + lane;   // gate n

  // h0 = user_embs[b, clip(length[b]-1,0)]; identical for all 32 rows
  int idx = length[b] - 1; if (idx < 0) idx = 0;
  const float u0 = user[((size_t)b*SS + idx)*DD + d];
  float h[2][4];
  #pragma unroll
  for (int mt = 0; mt < 2; ++mt)
    #pragma unroll
    for (int reg = 0; reg < 4; ++reg)
      h[mt][reg] = u0;

  // write h0 into hfrag[0] (A-fragment layout), owner-thread scatter
  const int tkk = d >> 5;
  const int slb = ((d >> 3) & 3) * 16;
  const int dj  = d & 7;
  {
    unsigned short hb = f2bf(u0);
    #pragma unroll
    for (int mt = 0; mt < 2; ++mt)
      #pragma unroll
      for (int reg = 0; reg < 4; ++reg)
        hfrag[0][((mt*8 + tkk)*64 + slb + q*4 + reg)*8 + dj] = hb;
  }

  // cooperative x-tile load: thread covers row = tid>>5, 8 d's at (tid&31)*8
  const int xrow = tid >> 5;        // 0..31
  const int xo   = tid & 31;        // which 8-wide d chunk
  const int xmt  = xrow >> 4;
  const int xtk  = xo >> 2;
  const int xsl  = (xo & 3)*16 + (xrow & 15);
  {
    const float4* p = (const float4*)(item + ((size_t)(nb + xrow)*KK + 0)*DD + xo*8);
    float4 a0 = p[0], a1 = p[1];
    unsigned short t[8];
    t[0]=f2bf(a0.x); t[1]=f2bf(a0.y); t[2]=f2bf(a0.z); t[3]=f2bf(a0.w);
    t[4]=f2bf(a1.x); t[5]=f2bf(a1.y); t[6]=f2bf(a1.z); t[7]=f2bf(a1.w);
    *(short8*)&xfrag[0][((xmt*8 + xtk)*64 + xsl)*8] = *(short8*)t;
  }

  // prime the weight prefetch ring with tk-slice `sk` (issues before the barrier)
  short8 wa0,wa1,wa2,wa3,wa4,wa5, wb0,wb1,wb2,wb3,wb4,wb5;
  {
    const int o_ = sk*64;
    wa0 = fw1[wq0+o_]; wa1 = fw1[wq1+o_]; wa2 = fw1[wq2+o_];
    wa3 = fwh[wq0+o_]; wa4 = fwh[wq1+o_]; wa5 = fwh[wq2+o_];
  }

  __syncthreads();

  const float bout = b_out[0];

#define MFMA16(A,Bv,C) __builtin_amdgcn_mfma_f32_16x16x32_bf16(A,Bv,C,0,0,0)
  // One tk sub-step: consume weight slice C*, prefetch slice ((TK)+1+sk)&7 into N*.
  // At TK==7 the prefetch wraps to slice sk == next step's first slice (addresses are
  // k-invariant), so the weight-load pipe never drains across the gate phase / barrier.
#define TKSTEP(C0,C1,C2,C3,C4,C5, N0,N1,N2,N3,N4,N5, TK) do{ \
      const int tkv_ = ((TK)+sk)&7; const int o_ = (((TK)+1+sk)&7)*64; \
      N0 = fw1[wq0+o_]; N1 = fw1[wq1+o_]; N2 = fw1[wq2+o_]; \
      N3 = fwh[wq0+o_]; N4 = fwh[wq1+o_]; N5 = fwh[wq2+o_]; \
      short8 ax0 = *(const short8*)&xfrag[cb][((    tkv_)*64 + lane)*8]; \
      short8 ax1 = *(const short8*)&xfrag[cb][((8 + tkv_)*64 + lane)*8]; \
      short8 ah0 = *(const short8*)&hfrag[cb][((    tkv_)*64 + lane)*8]; \
      short8 ah1 = *(const short8*)&hfrag[cb][((8 + tkv_)*64 + lane)*8]; \
      acc[0][0] = MFMA16(ax0,C0,acc[0][0]); acc[0][0] = MFMA16(ah0,C3,acc[0][0]); \
      acc[0][1] = MFMA16(ax0,C1,acc[0][1]); acc[0][1] = MFMA16(ah0,C4,acc[0][1]); \
      acc[0][2] = MFMA16(ax0,C2,acc[0][2]); acc[0][3] = MFMA16(ah0,C5,acc[0][3]); \
      acc[1][0] = MFMA16(ax1,C0,acc[1][0]); acc[1][0] = MFMA16(ah1,C3,acc[1][0]); \
      acc[1][1] = MFMA16(ax1,C1,acc[1][1]); acc[1][1] = MFMA16(ah1,C4,acc[1][1]); \
      acc[1][2] = MFMA16(ax1,C2,acc[1][2]); acc[1][3] = MFMA16(ah1,C5,acc[1][3]); \
    }while(0)

  for (int k = 0; k < KK; ++k){
    const int cb  = k & 1;
    const int nbf = cb ^ 1;

    // accumulators: [mt][kind]  kind: 0=r 1=z 2=i_n 3=h_n
    f32x4 acc[2][4];
    #pragma unroll
    for (int mt = 0; mt < 2; ++mt)
      #pragma unroll
      for (int kd = 0; kd < 4; ++kd){
        f32x4 z4 = {0.f, 0.f, 0.f, 0.f};
        acc[mt][kd] = z4;
      }

    // next x tile issued up-front: HBM latency hides under the whole MFMA phase
    float4 xn0, xn1;
    if (k < KK-1){
      const float4* p = (const float4*)(item + ((size_t)(nb + xrow)*KK + (k+1))*DD + xo*8);
      xn0 = p[0]; xn1 = p[1];
    }

    TKSTEP(wa0,wa1,wa2,wa3,wa4,wa5, wb0,wb1,wb2,wb3,wb4,wb5, 0);
    TKSTEP(wb0,wb1,wb2,wb3,wb4,wb5, wa0,wa1,wa2,wa3,wa4,wa5, 1);
    TKSTEP(wa0,wa1,wa2,wa3,wa4,wa5, wb0,wb1,wb2,wb3,wb4,wb5, 2);
    TKSTEP(wb0,wb1,wb2,wb3,wb4,wb5, wa0,wa1,wa2,wa3,wa4,wa5, 3);
    TKSTEP(wa0,wa1,wa2,wa3,wa4,wa5, wb0,wb1,wb2,wb3,wb4,wb5, 4);
    TKSTEP(wb0,wb1,wb2,wb3,wb4,wb5, wa0,wa1,wa2,wa3,wa4,wa5, 5);
    TKSTEP(wa0,wa1,wa2,wa3,wa4,wa5, wb0,wb1,wb2,wb3,wb4,wb5, 6);
    TKSTEP(wb0,wb1,wb2,wb3,wb4,wb5, wa0,wa1,wa2,wa3,wa4,wa5, 7);

    // gates — entirely in-register; raw v_rcp (1 ulp, fine vs bf16 noise) + v_med3 clamp
    float ypl[2][4];
    #pragma unroll
    for (int mt = 0; mt < 2; ++mt)
      #pragma unroll
      for (int reg = 0; reg < 4; ++reg){
        float rp = acc[mt][0][reg] + br_;
        float zp = acc[mt][1][reg] + bz_;
        float r  = __builtin_amdgcn_rcpf(1.f + __expf(-rp));
        float z  = __builtin_amdgcn_rcpf(1.f + __expf(-zp));
        float np = acc[mt][2][reg] + bin_ + r*(acc[mt][3][reg] + bhn_);
        np = __builtin_amdgcn_fmed3f(np, -30.f, 30.f);
        float e  = __expf(2.f*np);
        float n  = 1.f - 2.f*__builtin_amdgcn_rcpf(e + 1.f);   // tanh(np)
        float hv = (1.f - z)*n + z*h[mt][reg];
        h[mt][reg] = hv;
        ypl[mt][reg] = hv * wo_;
      }

    // y partial: reduce across the 16 cols of this wave's group
    #pragma unroll
    for (int mt = 0; mt < 2; ++mt)
      #pragma unroll
      for (int reg = 0; reg < 4; ++reg){
        float p = ypl[mt][reg];
        p += __shfl_xor(p, 1);
        p += __shfl_xor(p, 2);
        p += __shfl_xor(p, 4);
        p += __shfl_xor(p, 8);
        if (col == 0) yp[k % 3][w][mt][q][reg] = p;
      }

    // write h' (bf16) into hfrag[nbf] for next step
    #pragma unroll
    for (int mt = 0; mt < 2; ++mt)
      #pragma unroll
      for (int reg = 0; reg < 4; ++reg)
        hfrag[nbf][((mt*8 + tkk)*64 + slb + q*4 + reg)*8 + dj] = f2bf(h[mt][reg]);

    // write next x tile into xfrag[nbf]
    if (k < KK-1){
      unsigned short t[8];
      t[0]=f2bf(xn0.x); t[1]=f2bf(xn0.y); t[2]=f2bf(xn0.z); t[3]=f2bf(xn0.w);
      t[4]=f2bf(xn1.x); t[5]=f2bf(xn1.y); t[6]=f2bf(xn1.z); t[7]=f2bf(xn1.w);
      *(short8*)&xfrag[nbf][((xmt*8 + xtk)*64 + xsl)*8] = *(short8*)t;
    }

    // finalize y for step k-1 (yp[(k-1)%3] stable since previous barrier;
    // concurrent writes go to yp[k%3] which is a different buffer)
    if (k > 0 && tid < 32){
      float s = bout;
      #pragma unroll
      for (int ww = 0; ww < 16; ++ww)
        s += yp[(k-1) % 3][ww][tid >> 4][(tid >> 2) & 3][tid & 3];
      out[(size_t)(nb + tid)*KK + (k-1)] = s;
    }

    __syncthreads();   // single barrier per step
  }

  // finalize y for the last step
  if (tid < 32){
    float s = bout;
    #pragma unroll
    for (int ww = 0; ww < 16; ++ww)
      s += yp[(KK-1) % 3][ww][tid >> 4][(tid >> 2) & 3][tid & 3];
    out[(size_t)(nb + tid)*KK + (KK-1)] = s;
  }
}

extern "C" void kernel_launch(void* const* d_in, const int* in_sizes, int n_in,
                              void* d_out, int out_size, void* d_ws, size_t ws_size,
                              hipStream_t stream) {
  const float* item   = (const float*)d_in[0];
  const float* user   = (const float*)d_in[1];
  const float* W_ih   = (const float*)d_in[2];
  const float* W_hh   = (const float*)d_in[3];
  const float* b_ih   = (const float*)d_in[4];
  const float* b_hh   = (const float*)d_in[5];
  const float* w_out  = (const float*)d_in[6];
  const float* b_out  = (const float*)d_in[7];
  const int*   length = (const int*)d_in[8];
  unsigned short* ws  = (unsigned short*)d_ws;   // needs 768 KB
  float* out = (float*)d_out;

  hipLaunchKernelGGL(prep_weights, dim3((2*FRAG_ELEMS)/256), dim3(256), 0, stream,
                     W_ih, W_hh, ws);
  hipLaunchKernelGGL(gru_main, dim3(NBLK), dim3(NT), 0, stream,
                     item, user, b_ih, b_hh, w_out, b_out, length, ws, out);
}

// Round 4
// 476.623 us; speedup vs baseline: 1.1842x; 1.1370x over previous
//
#include <hip/hip_runtime.h>

#define BB 128
#define SS 64
#define KK 10
#define DD 256
#define NN (BB*SS)        // 8192 rows
#define ROWS 32           // rows per block
#define NBLK (NN/ROWS)    // 256 blocks = 1 per CU
#define NT 512            // 8 waves -> 2 waves/SIMD: 256-reg/wave budget

typedef __attribute__((ext_vector_type(8))) short short8;
typedef __attribute__((ext_vector_type(4))) float f32x4;

#define FRAG_ELEMS (48*8*64*8)   // 196608 bf16 values per weight matrix

__device__ __forceinline__ unsigned short f2bf(float f){
  union { float f; unsigned u; } v; v.f = f;
  unsigned r = (v.u + 0x7FFFu + ((v.u >> 16) & 1u)) >> 16;
  return (unsigned short)r;
}

// Pre-swizzle W_ih[:, :D] and W_hh into bf16 MFMA B-fragment order:
// frag value at (tn, tk, lane, j) = W[c = tn*16 + (lane&15)][d = tk*32 + (lane>>4)*8 + j]
// stored flat at ((tn*8+tk)*64 + lane)*8 + j.  FW1 first, FWhh second.
__global__ void prep_weights(const float* __restrict__ Wih,
                             const float* __restrict__ Whh,
                             unsigned short* __restrict__ fw){
  int id = blockIdx.x * 256 + threadIdx.x;     // 0 .. 2*FRAG_ELEMS-1
  int arr = (id >= FRAG_ELEMS);
  int r = arr ? (id - FRAG_ELEMS) : id;
  int j  = r & 7;
  int l  = (r >> 3) & 63;
  int tk = (r >> 9) & 7;
  int tn = r >> 12;                            // 0..47
  int c  = tn * 16 + (l & 15);                 // 0..767
  int d  = tk * 32 + ((l >> 4) << 3) + j;      // 0..255
  float v = arr ? Whh[c * 256 + d] : Wih[c * 512 + d];
  fw[id] = f2bf(v);
}

// 512-thr blocks: 8 waves = 2/SIMD residency minimum -> 512/2 = 256 regs/wave
// budget. (1024-thr blocks force 4 waves/SIMD residency -> hard 128-total cap
// = 64 arch VGPRs; the prefetch ring spilled to scratch there regardless of
// __launch_bounds__. Block shape, not launch_bounds, was the wall.)
__global__ __launch_bounds__(NT, 2) void gru_main(
    const float* __restrict__ item, const float* __restrict__ user,
    const float* __restrict__ b_ih, const float* __restrict__ b_hh,
    const float* __restrict__ w_out, const float* __restrict__ b_out,
    const int* __restrict__ length, const unsigned short* __restrict__ ws,
    float* __restrict__ out)
{
  // A-fragment layout: elem (mt, tk, lane, j) at ((mt*8+tk)*64+lane)*8+j
  // double-buffered so one barrier/step suffices
  __shared__ unsigned short xfrag[2][2*8*64*8];   // 32 KB
  __shared__ unsigned short hfrag[2][2*8*64*8];   // 32 KB
  __shared__ float yp[3][16][2][4][4];            // 6 KB, triple-buffered

  const int tid  = threadIdx.x;
  const int lane = tid & 63;
  const int w    = tid >> 6;        // wave 0..7; owns column groups w and w+8
  const int col  = lane & 15;       // C-layout col
  const int q    = lane >> 4;       // quad
  const int nb   = blockIdx.x * ROWS;
  const int b    = nb / SS;         // one user per block (32 | 64)
  const int sk   = blockIdx.x & 7;  // tk read-order skew: decorrelate L2 bursts

  const short8* fw1 = (const short8*)ws;
  const short8* fwh = fw1 + (FRAG_ELEMS/8);

  // per-column constants for the 2 owned channels: d0 = w*16+col, d1 = d0+128
  const int d0 = w*16 + col;
  const int d1 = d0 + 128;
  float br_g[2], bz_g[2], bin_g[2], bhn_g[2], wo_g[2];
  br_g[0]  = b_ih[d0]       + b_hh[d0];       br_g[1]  = b_ih[d1]       + b_hh[d1];
  bz_g[0]  = b_ih[256 + d0] + b_hh[256 + d0]; bz_g[1]  = b_ih[256 + d1] + b_hh[256 + d1];
  bin_g[0] = b_ih[512 + d0];                  bin_g[1] = b_ih[512 + d1];
  bhn_g[0] = b_hh[512 + d0];                  bhn_g[1] = b_hh[512 + d1];
  wo_g[0]  = w_out[d0];                       wo_g[1]  = w_out[d1];

  // weight fragment flat offsets (short8 units): frag(tn,tk) = fw[tn*512 + tk*64 + lane]
  // group g0=w gates r/z/n at wq0/wq1/wq2; group g1=w+8 at +8*512 = +4096.
  const int wq0 = (w     )*512 + lane;
  const int wq1 = (16 + w)*512 + lane;
  const int wq2 = (32 + w)*512 + lane;

  // h0 = user_embs[b, clip(length[b]-1,0)]; identical for all 32 rows
  int idx = length[b] - 1; if (idx < 0) idx = 0;
  float u0g[2];
  u0g[0] = user[((size_t)b*SS + idx)*DD + d0];
  u0g[1] = user[((size_t)b*SS + idx)*DD + d1];
  float h[2][2][4];                 // [mt][g][reg]
  #pragma unroll
  for (int mt = 0; mt < 2; ++mt)
    #pragma unroll
    for (int g = 0; g < 2; ++g)
      #pragma unroll
      for (int reg = 0; reg < 4; ++reg)
        h[mt][g][reg] = u0g[g];

  // owner-thread scatter indices: d1's tk-block = tkk+4, slb/dj identical (d1=d0+128)
  const int tkk = d0 >> 5;          // 0..3
  const int slb = ((d0 >> 3) & 3) * 16;
  const int dj  = d0 & 7;
  #pragma unroll
  for (int g = 0; g < 2; ++g){
    unsigned short hb = f2bf(u0g[g]);
    #pragma unroll
    for (int mt = 0; mt < 2; ++mt)
      #pragma unroll
      for (int reg = 0; reg < 4; ++reg)
        hfrag[0][((mt*8 + tkk + 4*g)*64 + slb + q*4 + reg)*8 + dj] = hb;
  }

  // cooperative x-tile load: 512 threads x 2 chunks.
  // chunk A: row = tid>>5 (0..15, xmt=0); chunk B: row+16 (xmt=1); same xo/xsl.
  const int xrow = tid >> 5;        // 0..15
  const int xo   = tid & 31;        // which 8-wide d chunk
  const int xtk  = xo >> 2;
  const int xsl  = (xo & 3)*16 + xrow;
  {
    const float4* pA = (const float4*)(item + ((size_t)(nb + xrow     )*KK + 0)*DD + xo*8);
    const float4* pB = (const float4*)(item + ((size_t)(nb + xrow + 16)*KK + 0)*DD + xo*8);
    float4 a0 = pA[0], a1 = pA[1], c0 = pB[0], c1 = pB[1];
    unsigned short t[8];
    t[0]=f2bf(a0.x); t[1]=f2bf(a0.y); t[2]=f2bf(a0.z); t[3]=f2bf(a0.w);
    t[4]=f2bf(a1.x); t[5]=f2bf(a1.y); t[6]=f2bf(a1.z); t[7]=f2bf(a1.w);
    *(short8*)&xfrag[0][((0*8 + xtk)*64 + xsl)*8] = *(short8*)t;
    t[0]=f2bf(c0.x); t[1]=f2bf(c0.y); t[2]=f2bf(c0.z); t[3]=f2bf(c0.w);
    t[4]=f2bf(c1.x); t[5]=f2bf(c1.y); t[6]=f2bf(c1.z); t[7]=f2bf(c1.w);
    *(short8*)&xfrag[0][((1*8 + xtk)*64 + xsl)*8] = *(short8*)t;
  }

  // ring register sets: 12 fragments each (2 groups x {r,z,n} x {W1,Whh})
  short8 A0,A1,A2,A3,A4,A5,A6,A7,A8,A9,A10,A11;
  short8 B0,B1,B2,B3,B4,B5,B6,B7,B8,B9,B10,B11;

#define LOADSET(P, o_) do{ \
    P##0 = fw1[wq0+(o_)];      P##1 = fw1[wq1+(o_)];      P##2 = fw1[wq2+(o_)]; \
    P##3 = fwh[wq0+(o_)];      P##4 = fwh[wq1+(o_)];      P##5 = fwh[wq2+(o_)]; \
    P##6 = fw1[wq0+4096+(o_)]; P##7 = fw1[wq1+4096+(o_)]; P##8 = fw1[wq2+4096+(o_)]; \
    P##9 = fwh[wq0+4096+(o_)]; P##10= fwh[wq1+4096+(o_)]; P##11= fwh[wq2+4096+(o_)]; \
  }while(0)

  // prime the ring with tk-slice `sk` (issues before the barrier)
  LOADSET(A, sk*64);

  __syncthreads();

  const float bout = b_out[0];

#define MFMA16(Aop,Bop,C) __builtin_amdgcn_mfma_f32_16x16x32_bf16(Aop,Bop,C,0,0,0)
  // consume set C for slice (TK+sk)&7, prefetch slice (TK+1+sk)&7 into N.
  // At TK==7 the prefetch wraps to slice sk == next step's first slice, so
  // weight loads stay in flight across the gate phase + barrier.
#define TKSTEP(C, N, TK) do{ \
    const int tkv_ = ((TK)+sk)&7; const int o_ = (((TK)+1+sk)&7)*64; \
    LOADSET(N, o_); \
    short8 ax0 = *(const short8*)&xfrag[cb][((    tkv_)*64 + lane)*8]; \
    short8 ax1 = *(const short8*)&xfrag[cb][((8 + tkv_)*64 + lane)*8]; \
    short8 ah0 = *(const short8*)&hfrag[cb][((    tkv_)*64 + lane)*8]; \
    short8 ah1 = *(const short8*)&hfrag[cb][((8 + tkv_)*64 + lane)*8]; \
    acc[0][0][0]=MFMA16(ax0,C##0,acc[0][0][0]); acc[0][0][1]=MFMA16(ax0,C##1,acc[0][0][1]); \
    acc[0][0][2]=MFMA16(ax0,C##2,acc[0][0][2]); \
    acc[0][1][0]=MFMA16(ax0,C##6,acc[0][1][0]); acc[0][1][1]=MFMA16(ax0,C##7,acc[0][1][1]); \
    acc[0][1][2]=MFMA16(ax0,C##8,acc[0][1][2]); \
    acc[1][0][0]=MFMA16(ax1,C##0,acc[1][0][0]); acc[1][0][1]=MFMA16(ax1,C##1,acc[1][0][1]); \
    acc[1][0][2]=MFMA16(ax1,C##2,acc[1][0][2]); \
    acc[1][1][0]=MFMA16(ax1,C##6,acc[1][1][0]); acc[1][1][1]=MFMA16(ax1,C##7,acc[1][1][1]); \
    acc[1][1][2]=MFMA16(ax1,C##8,acc[1][1][2]); \
    acc[0][0][0]=MFMA16(ah0,C##3,acc[0][0][0]); acc[0][0][1]=MFMA16(ah0,C##4,acc[0][0][1]); \
    acc[0][0][3]=MFMA16(ah0,C##5,acc[0][0][3]); \
    acc[0][1][0]=MFMA16(ah0,C##9,acc[0][1][0]); acc[0][1][1]=MFMA16(ah0,C##10,acc[0][1][1]); \
    acc[0][1][3]=MFMA16(ah0,C##11,acc[0][1][3]); \
    acc[1][0][0]=MFMA16(ah1,C##3,acc[1][0][0]); acc[1][0][1]=MFMA16(ah1,C##4,acc[1][0][1]); \
    acc[1][0][3]=MFMA16(ah1,C##5,acc[1][0][3]); \
    acc[1][1][0]=MFMA16(ah1,C##9,acc[1][1][0]); acc[1][1][1]=MFMA16(ah1,C##10,acc[1][1][1]); \
    acc[1][1][3]=MFMA16(ah1,C##11,acc[1][1][3]); \
  }while(0)

  for (int k = 0; k < KK; ++k){
    const int cb  = k & 1;
    const int nbf = cb ^ 1;

    // accumulators: [mt][g][kind]  kind: 0=r 1=z 2=i_n 3=h_n
    f32x4 acc[2][2][4];
    #pragma unroll
    for (int mt = 0; mt < 2; ++mt)
      #pragma unroll
      for (int g = 0; g < 2; ++g)
        #pragma unroll
        for (int kd = 0; kd < 4; ++kd){
          f32x4 z4 = {0.f, 0.f, 0.f, 0.f};
          acc[mt][g][kd] = z4;
        }

    TKSTEP(A, B, 0);
    TKSTEP(B, A, 1);
    TKSTEP(A, B, 2);
    TKSTEP(B, A, 3);
    TKSTEP(A, B, 4);
    TKSTEP(B, A, 5);
    TKSTEP(A, B, 6);
    TKSTEP(B, A, 7);

    // prefetch next x tile into registers (HBM/L3 latency hidden behind gates)
    float4 xn0, xn1, xn2, xn3;
    if (k < KK-1){
      const float4* pA = (const float4*)(item + ((size_t)(nb + xrow     )*KK + (k+1))*DD + xo*8);
      const float4* pB = (const float4*)(item + ((size_t)(nb + xrow + 16)*KK + (k+1))*DD + xo*8);
      xn0 = pA[0]; xn1 = pA[1]; xn2 = pB[0]; xn3 = pB[1];
    }

    // gates — entirely in-register (v_rcp + v_med3)
    float ypl[2][2][4];
    #pragma unroll
    for (int mt = 0; mt < 2; ++mt)
      #pragma unroll
      for (int g = 0; g < 2; ++g)
        #pragma unroll
        for (int reg = 0; reg < 4; ++reg){
          float rp = acc[mt][g][0][reg] + br_g[g];
          float zp = acc[mt][g][1][reg] + bz_g[g];
          float r  = __builtin_amdgcn_rcpf(1.f + __expf(-rp));
          float z  = __builtin_amdgcn_rcpf(1.f + __expf(-zp));
          float np = acc[mt][g][2][reg] + bin_g[g] + r*(acc[mt][g][3][reg] + bhn_g[g]);
          np = __builtin_amdgcn_fmed3f(np, -30.f, 30.f);
          float e  = __expf(2.f*np);
          float n  = 1.f - 2.f*__builtin_amdgcn_rcpf(e + 1.f);   // tanh(np)
          float hv = (1.f - z)*n + z*h[mt][g][reg];
          h[mt][g][reg] = hv;
          ypl[mt][g][reg] = hv * wo_g[g];
        }

    // y partial: reduce across the 16 cols of each owned group
    #pragma unroll
    for (int mt = 0; mt < 2; ++mt)
      #pragma unroll
      for (int g = 0; g < 2; ++g)
        #pragma unroll
        for (int reg = 0; reg < 4; ++reg){
          float p = ypl[mt][g][reg];
          p += __shfl_xor(p, 1);
          p += __shfl_xor(p, 2);
          p += __shfl_xor(p, 4);
          p += __shfl_xor(p, 8);
          if (col == 0) yp[k % 3][w + 8*g][mt][q][reg] = p;
        }

    // write h' (bf16) into hfrag[nbf] for next step
    #pragma unroll
    for (int mt = 0; mt < 2; ++mt)
      #pragma unroll
      for (int g = 0; g < 2; ++g)
        #pragma unroll
        for (int reg = 0; reg < 4; ++reg)
          hfrag[nbf][((mt*8 + tkk + 4*g)*64 + slb + q*4 + reg)*8 + dj] = f2bf(h[mt][g][reg]);

    // write next x tile into xfrag[nbf]
    if (k < KK-1){
      unsigned short t[8];
      t[0]=f2bf(xn0.x); t[1]=f2bf(xn0.y); t[2]=f2bf(xn0.z); t[3]=f2bf(xn0.w);
      t[4]=f2bf(xn1.x); t[5]=f2bf(xn1.y); t[6]=f2bf(xn1.z); t[7]=f2bf(xn1.w);
      *(short8*)&xfrag[nbf][((0*8 + xtk)*64 + xsl)*8] = *(short8*)t;
      t[0]=f2bf(xn2.x); t[1]=f2bf(xn2.y); t[2]=f2bf(xn2.z); t[3]=f2bf(xn2.w);
      t[4]=f2bf(xn3.x); t[5]=f2bf(xn3.y); t[6]=f2bf(xn3.z); t[7]=f2bf(xn3.w);
      *(short8*)&xfrag[nbf][((1*8 + xtk)*64 + xsl)*8] = *(short8*)t;
    }

    // finalize y for step k-1 (yp[(k-1)%3] stable since previous barrier;
    // concurrent writes go to yp[k%3] which is a different buffer)
    if (k > 0 && tid < 32){
      float s = bout;
      #pragma unroll
      for (int ww = 0; ww < 16; ++ww)
        s += yp[(k-1) % 3][ww][tid >> 4][(tid >> 2) & 3][tid & 3];
      out[(size_t)(nb + tid)*KK + (k-1)] = s;
    }

    __syncthreads();   // single barrier per step
  }

  // finalize y for the last step
  if (tid < 32){
    float s = bout;
    #pragma unroll
    for (int ww = 0; ww < 16; ++ww)
      s += yp[(KK-1) % 3][ww][tid >> 4][(tid >> 2) & 3][tid & 3];
    out[(size_t)(nb + tid)*KK + (KK-1)] = s;
  }
}

extern "C" void kernel_launch(void* const* d_in, const int* in_sizes, int n_in,
                              void* d_out, int out_size, void* d_ws, size_t ws_size,
                              hipStream_t stream) {
  const float* item   = (const float*)d_in[0];
  const float* user   = (const float*)d_in[1];
  const float* W_ih   = (const float*)d_in[2];
  const float* W_hh   = (const float*)d_in[3];
  const float* b_ih   = (const float*)d_in[4];
  const float* b_hh   = (const float*)d_in[5];
  const float* w_out  = (const float*)d_in[6];
  const float* b_out  = (const float*)d_in[7];
  const int*   length = (const int*)d_in[8];
  unsigned short* ws  = (unsigned short*)d_ws;   // needs 768 KB
  float* out = (float*)d_out;

  hipLaunchKernelGGL(prep_weights, dim3((2*FRAG_ELEMS)/256), dim3(256), 0, stream,
                     W_ih, W_hh, ws);
  hipLaunchKernelGGL(gru_main, dim3(NBLK), dim3(NT), 0, stream,
                     item, user, b_ih, b_hh, w_out, b_out, length, ws, out);
}

// Round 5
// 347.479 us; speedup vs baseline: 1.6243x; 1.3717x over previous
//
#include <hip/hip_runtime.h>

#define BB 128
#define SS 64
#define KK 10
#define DD 256
#define NN (BB*SS)        // 8192 rows
#define ROWS 64           // one full user per block
#define NBLK (NN/ROWS)    // 128 blocks: HALVES chip-wide L2 weight traffic
#define NT 512            // 8 waves -> 2 waves/SIMD -> 256-reg/wave budget

typedef __attribute__((ext_vector_type(8))) short short8;
typedef __attribute__((ext_vector_type(4))) float f32x4;

#define FRAG_ELEMS (48*8*64*8)   // 196608 bf16 values per weight matrix

__device__ __forceinline__ unsigned short f2bf(float f){
  union { float f; unsigned u; } v; v.f = f;
  unsigned r = (v.u + 0x7FFFu + ((v.u >> 16) & 1u)) >> 16;
  return (unsigned short)r;
}

// Pre-swizzle W_ih[:, :D] and W_hh into bf16 MFMA B-fragment order:
// frag value at (tn, tk, lane, j) = W[c = tn*16 + (lane&15)][d = tk*32 + (lane>>4)*8 + j]
// stored flat at ((tn*8+tk)*64 + lane)*8 + j.  FW1 first, FWhh second.
__global__ void prep_weights(const float* __restrict__ Wih,
                             const float* __restrict__ Whh,
                             unsigned short* __restrict__ fw){
  int id = blockIdx.x * 256 + threadIdx.x;     // 0 .. 2*FRAG_ELEMS-1
  int arr = (id >= FRAG_ELEMS);
  int r = arr ? (id - FRAG_ELEMS) : id;
  int j  = r & 7;
  int l  = (r >> 3) & 63;
  int tk = (r >> 9) & 7;
  int tn = r >> 12;                            // 0..47
  int c  = tn * 16 + (l & 15);                 // 0..767
  int d  = tk * 32 + ((l >> 4) << 3) + j;      // 0..255
  float v = arr ? Whh[c * 256 + d] : Wih[c * 512 + d];
  fw[id] = f2bf(v);
}

// 64 rows/block, 128 blocks: per-step chip weight traffic = 128 x 768 KB
// = 100 MB (was 201), per-XCD L2 floor 2.9 us/step. Each weight fragment
// feeds 4 row-tiles (48 MFMA per 12 loads per tk) -> 4x latency cover.
// No register prefetch ring (spilled twice at tighter budgets); rolled tk
// loop + 2-wave TLP per SIMD covers L2 latency (233cy MFMA vs ~200cy load).
__global__ __launch_bounds__(NT, 2) void gru_main(
    const float* __restrict__ item, const float* __restrict__ user,
    const float* __restrict__ b_ih, const float* __restrict__ b_hh,
    const float* __restrict__ w_out, const float* __restrict__ b_out,
    const int* __restrict__ length, const unsigned short* __restrict__ ws,
    float* __restrict__ out)
{
  // A-fragment layout: elem (mt, tk, lane, j) at ((mt*8+tk)*64+lane)*8+j, mt 0..3
  __shared__ unsigned short xfrag[2][4*8*64*8];   // 64 KB
  __shared__ unsigned short hfrag[2][4*8*64*8];   // 64 KB
  __shared__ float yp[3][16][4][4][4];            // 12 KB  (total 140 KB)

  const int tid  = threadIdx.x;
  const int lane = tid & 63;
  const int w    = tid >> 6;        // wave 0..7; owns column groups w and w+8
  const int col  = lane & 15;       // C-layout col
  const int q    = lane >> 4;       // quad
  const int nb   = blockIdx.x * ROWS;
  const int b    = blockIdx.x;      // exactly one user per block (ROWS == SS)
  const int sk   = blockIdx.x & 7;  // tk read-order skew: decorrelate L2 bursts

  const short8* fw1 = (const short8*)ws;
  const short8* fwh = fw1 + (FRAG_ELEMS/8);

  // per-column constants for the 2 owned channels: d0 = w*16+col (0..127), d1 = d0+128
  const int d0 = w*16 + col;
  const int d1 = d0 + 128;
  float br_g[2], bz_g[2], bin_g[2], bhn_g[2], wo_g[2];
  br_g[0]  = b_ih[d0]       + b_hh[d0];       br_g[1]  = b_ih[d1]       + b_hh[d1];
  bz_g[0]  = b_ih[256 + d0] + b_hh[256 + d0]; bz_g[1]  = b_ih[256 + d1] + b_hh[256 + d1];
  bin_g[0] = b_ih[512 + d0];                  bin_g[1] = b_ih[512 + d1];
  bhn_g[0] = b_hh[512 + d0];                  bhn_g[1] = b_hh[512 + d1];
  wo_g[0]  = w_out[d0];                       wo_g[1]  = w_out[d1];

  // weight fragment flat offsets (short8 units): frag(tn,tk) = fw[tn*512 + tk*64 + lane]
  // group g0=w gates r/z/n at wq0/wq1/wq2; group g1=w+8 at +8*512 = +4096.
  const int wq0 = (w     )*512 + lane;
  const int wq1 = (16 + w)*512 + lane;
  const int wq2 = (32 + w)*512 + lane;

  // h0 = user_embs[b, clip(length[b]-1,0)]; identical for all 64 rows
  int idx = length[b] - 1; if (idx < 0) idx = 0;
  float u0g[2];
  u0g[0] = user[((size_t)b*SS + idx)*DD + d0];
  u0g[1] = user[((size_t)b*SS + idx)*DD + d1];
  float h[4][2][4];                 // [mt][g][reg]
  #pragma unroll
  for (int mt = 0; mt < 4; ++mt)
    #pragma unroll
    for (int g = 0; g < 2; ++g)
      #pragma unroll
      for (int reg = 0; reg < 4; ++reg)
        h[mt][g][reg] = u0g[g];

  // owner-thread scatter indices: d1's tk-block = tkk+4, slb/dj identical (d1=d0+128)
  const int tkk = d0 >> 5;          // 0..3
  const int slb = ((d0 >> 3) & 3) * 16;
  const int dj  = d0 & 7;
  #pragma unroll
  for (int g = 0; g < 2; ++g){
    unsigned short hb = f2bf(u0g[g]);
    #pragma unroll
    for (int mt = 0; mt < 4; ++mt)
      #pragma unroll
      for (int reg = 0; reg < 4; ++reg)
        hfrag[0][((mt*8 + tkk + 4*g)*64 + slb + q*4 + reg)*8 + dj] = hb;
  }

  // cooperative x-tile load: thread covers rows xrow+16*mt (mt 0..3), chunk xo
  const int xrow = tid >> 5;        // 0..15
  const int xo   = tid & 31;        // which 8-wide d chunk
  const int xtk  = xo >> 2;
  const int xsl  = (xo & 3)*16 + xrow;
  #pragma unroll
  for (int mt = 0; mt < 4; ++mt){
    const float4* p = (const float4*)(item + ((size_t)(nb + mt*16 + xrow)*KK + 0)*DD + xo*8);
    float4 a0 = p[0], a1 = p[1];
    unsigned short t[8];
    t[0]=f2bf(a0.x); t[1]=f2bf(a0.y); t[2]=f2bf(a0.z); t[3]=f2bf(a0.w);
    t[4]=f2bf(a1.x); t[5]=f2bf(a1.y); t[6]=f2bf(a1.z); t[7]=f2bf(a1.w);
    *(short8*)&xfrag[0][((mt*8 + xtk)*64 + xsl)*8] = *(short8*)t;
  }

  __syncthreads();

  const float bout = b_out[0];

#define MFMA16(Aop,Bop,C) __builtin_amdgcn_mfma_f32_16x16x32_bf16(Aop,Bop,C,0,0,0)

  for (int k = 0; k < KK; ++k){
    const int cb  = k & 1;
    const int nbf = cb ^ 1;

    // accumulators: [mt][g][kind]  kind: 0=r 1=z 2=i_n 3=h_n  (128 regs)
    f32x4 acc[4][2][4];
    #pragma unroll
    for (int mt = 0; mt < 4; ++mt)
      #pragma unroll
      for (int g = 0; g < 2; ++g)
        #pragma unroll
        for (int kd = 0; kd < 4; ++kd){
          f32x4 z4 = {0.f, 0.f, 0.f, 0.f};
          acc[mt][g][kd] = z4;
        }

    #pragma unroll 1
    for (int tk = 0; tk < 8; ++tk){
      const int tkv = (tk + sk) & 7;
      short8 ax[4], ah[4];
      #pragma unroll
      for (int mt = 0; mt < 4; ++mt){
        ax[mt] = *(const short8*)&xfrag[cb][((mt*8 + tkv)*64 + lane)*8];
        ah[mt] = *(const short8*)&hfrag[cb][((mt*8 + tkv)*64 + lane)*8];
      }
      #pragma unroll
      for (int g = 0; g < 2; ++g){
        const int base = g*4096 + tkv*64;
        short8 w1r = fw1[wq0+base], w1z = fw1[wq1+base], w1n = fw1[wq2+base];
        short8 whr = fwh[wq0+base], whz = fwh[wq1+base], whn = fwh[wq2+base];
        #pragma unroll
        for (int mt = 0; mt < 4; ++mt){
          acc[mt][g][0] = MFMA16(ax[mt], w1r, acc[mt][g][0]);
          acc[mt][g][1] = MFMA16(ax[mt], w1z, acc[mt][g][1]);
          acc[mt][g][2] = MFMA16(ax[mt], w1n, acc[mt][g][2]);
          acc[mt][g][0] = MFMA16(ah[mt], whr, acc[mt][g][0]);
          acc[mt][g][1] = MFMA16(ah[mt], whz, acc[mt][g][1]);
          acc[mt][g][3] = MFMA16(ah[mt], whn, acc[mt][g][3]);
        }
      }
    }

    // prefetch next x tile into registers (acc is dead during gates)
    float4 xn[4][2];
    if (k < KK-1){
      #pragma unroll
      for (int mt = 0; mt < 4; ++mt){
        const float4* p = (const float4*)(item + ((size_t)(nb + mt*16 + xrow)*KK + (k+1))*DD + xo*8);
        xn[mt][0] = p[0]; xn[mt][1] = p[1];
      }
    }

    // gates — entirely in-register (v_rcp + v_med3)
    float ypl[4][2][4];
    #pragma unroll
    for (int mt = 0; mt < 4; ++mt)
      #pragma unroll
      for (int g = 0; g < 2; ++g)
        #pragma unroll
        for (int reg = 0; reg < 4; ++reg){
          float rp = acc[mt][g][0][reg] + br_g[g];
          float zp = acc[mt][g][1][reg] + bz_g[g];
          float r  = __builtin_amdgcn_rcpf(1.f + __expf(-rp));
          float z  = __builtin_amdgcn_rcpf(1.f + __expf(-zp));
          float np = acc[mt][g][2][reg] + bin_g[g] + r*(acc[mt][g][3][reg] + bhn_g[g]);
          np = __builtin_amdgcn_fmed3f(np, -30.f, 30.f);
          float e  = __expf(2.f*np);
          float n  = 1.f - 2.f*__builtin_amdgcn_rcpf(e + 1.f);   // tanh(np)
          float hv = (1.f - z)*n + z*h[mt][g][reg];
          h[mt][g][reg] = hv;
          ypl[mt][g][reg] = hv * wo_g[g];
        }

    // y partial: reduce across the 16 cols of each owned group
    #pragma unroll
    for (int mt = 0; mt < 4; ++mt)
      #pragma unroll
      for (int g = 0; g < 2; ++g)
        #pragma unroll
        for (int reg = 0; reg < 4; ++reg){
          float p = ypl[mt][g][reg];
          p += __shfl_xor(p, 1);
          p += __shfl_xor(p, 2);
          p += __shfl_xor(p, 4);
          p += __shfl_xor(p, 8);
          if (col == 0) yp[k % 3][w + 8*g][mt][q][reg] = p;
        }

    // write h' (bf16) into hfrag[nbf] for next step
    #pragma unroll
    for (int mt = 0; mt < 4; ++mt)
      #pragma unroll
      for (int g = 0; g < 2; ++g)
        #pragma unroll
        for (int reg = 0; reg < 4; ++reg)
          hfrag[nbf][((mt*8 + tkk + 4*g)*64 + slb + q*4 + reg)*8 + dj] = f2bf(h[mt][g][reg]);

    // write next x tile into xfrag[nbf]
    if (k < KK-1){
      #pragma unroll
      for (int mt = 0; mt < 4; ++mt){
        unsigned short t[8];
        t[0]=f2bf(xn[mt][0].x); t[1]=f2bf(xn[mt][0].y); t[2]=f2bf(xn[mt][0].z); t[3]=f2bf(xn[mt][0].w);
        t[4]=f2bf(xn[mt][1].x); t[5]=f2bf(xn[mt][1].y); t[6]=f2bf(xn[mt][1].z); t[7]=f2bf(xn[mt][1].w);
        *(short8*)&xfrag[nbf][((mt*8 + xtk)*64 + xsl)*8] = *(short8*)t;
      }
    }

    // finalize y for step k-1 (yp[(k-1)%3] stable since previous barrier)
    if (k > 0 && tid < 64){
      float s = bout;
      #pragma unroll
      for (int ww = 0; ww < 16; ++ww)
        s += yp[(k-1) % 3][ww][tid >> 4][(tid >> 2) & 3][tid & 3];
      out[(size_t)(nb + tid)*KK + (k-1)] = s;
    }

    __syncthreads();   // single barrier per step
  }

  // finalize y for the last step
  if (tid < 64){
    float s = bout;
    #pragma unroll
    for (int ww = 0; ww < 16; ++ww)
      s += yp[(KK-1) % 3][ww][tid >> 4][(tid >> 2) & 3][tid & 3];
    out[(size_t)(nb + tid)*KK + (KK-1)] = s;
  }
}

extern "C" void kernel_launch(void* const* d_in, const int* in_sizes, int n_in,
                              void* d_out, int out_size, void* d_ws, size_t ws_size,
                              hipStream_t stream) {
  const float* item   = (const float*)d_in[0];
  const float* user   = (const float*)d_in[1];
  const float* W_ih   = (const float*)d_in[2];
  const float* W_hh   = (const float*)d_in[3];
  const float* b_ih   = (const float*)d_in[4];
  const float* b_hh   = (const float*)d_in[5];
  const float* w_out  = (const float*)d_in[6];
  const float* b_out  = (const float*)d_in[7];
  const int*   length = (const int*)d_in[8];
  unsigned short* ws  = (unsigned short*)d_ws;   // needs 768 KB
  float* out = (float*)d_out;

  hipLaunchKernelGGL(prep_weights, dim3((2*FRAG_ELEMS)/256), dim3(256), 0, stream,
                     W_ih, W_hh, ws);
  hipLaunchKernelGGL(gru_main, dim3(NBLK), dim3(NT), 0, stream,
                     item, user, b_ih, b_hh, w_out, b_out, length, ws, out);
}

// Round 6
// 218.142 us; speedup vs baseline: 2.5873x; 1.5929x over previous
//
#include <hip/hip_runtime.h>

#define BB 128
#define SS 64
#define KK 10
#define DD 256
#define NN (BB*SS)        // 8192 rows
#define ROWS 32           // rows per block
#define NBLK (NN/ROWS)    // 256 blocks = 1 per CU
#define NT 1024           // 16 waves per block -> 4 waves/SIMD

typedef __attribute__((ext_vector_type(8))) short short8;
typedef __attribute__((ext_vector_type(4))) float f32x4;

#define FRAG_ELEMS (48*8*64*8)   // 196608 bf16 values per weight matrix

__device__ __forceinline__ unsigned short f2bf(float f){
  union { float f; unsigned u; } v; v.f = f;
  unsigned r = (v.u + 0x7FFFu + ((v.u >> 16) & 1u)) >> 16;
  return (unsigned short)r;
}

// Pre-swizzle W_ih[:, :D] and W_hh into bf16 MFMA B-fragment order:
// frag value at (tn, tk, lane, j) = W[c = tn*16 + (lane&15)][d = tk*32 + (lane>>4)*8 + j]
// stored flat at ((tn*8+tk)*64 + lane)*8 + j.  FW1 first, FWhh second.
__global__ void prep_weights(const float* __restrict__ Wih,
                             const float* __restrict__ Whh,
                             unsigned short* __restrict__ fw){
  int id = blockIdx.x * 256 + threadIdx.x;     // 0 .. 2*FRAG_ELEMS-1
  int arr = (id >= FRAG_ELEMS);
  int r = arr ? (id - FRAG_ELEMS) : id;
  int j  = r & 7;
  int l  = (r >> 3) & 63;
  int tk = (r >> 9) & 7;
  int tn = r >> 12;                            // 0..47
  int c  = tn * 16 + (l & 15);                 // 0..767
  int d  = tk * 32 + ((l >> 4) << 3) + j;      // 0..255
  float v = arr ? Whh[c * 256 + d] : Wih[c * 512 + d];
  fw[id] = f2bf(v);
}

// Baseline geometry (proven 137us): 256 blocks x 1024 thr, 4 waves/SIMD,
// wave owns 1 column group, acc = 32 AGPR, arch VGPR ~64.
// Register-ring prefetch is OFF (spilled at this budget twice: 64-cap and
// 128-cap configs both scratch-spilled). Latency levers here are all
// compiler-discretionary: unroll-4 tk pipelining, hoisted x-prefetch,
// tk-skew, setprio around MFMA, rcp/med3 gates.
__global__ __launch_bounds__(NT, 4) void gru_main(
    const float* __restrict__ item, const float* __restrict__ user,
    const float* __restrict__ b_ih, const float* __restrict__ b_hh,
    const float* __restrict__ w_out, const float* __restrict__ b_out,
    const int* __restrict__ length, const unsigned short* __restrict__ ws,
    float* __restrict__ out)
{
  // A-fragment layout: elem (mt, tk, lane, j) at ((mt*8+tk)*64+lane)*8+j
  // double-buffered so one barrier/step suffices
  __shared__ unsigned short xfrag[2][2*8*64*8];   // 32 KB
  __shared__ unsigned short hfrag[2][2*8*64*8];   // 32 KB
  __shared__ float yp[3][16][2][4][4];            // 6 KB, triple-buffered

  const int tid  = threadIdx.x;
  const int lane = tid & 63;
  const int w    = tid >> 6;        // wave 0..15 == column group g
  const int col  = lane & 15;       // C-layout col
  const int q    = lane >> 4;       // quad
  const int nb   = blockIdx.x * ROWS;
  const int b    = nb / SS;         // one user per block (32 | 64)
  const int sk   = blockIdx.x & 7;  // tk read-order skew: decorrelate L2 bursts

  const short8* fw1 = (const short8*)ws;
  const short8* fwh = fw1 + (FRAG_ELEMS/8);

  // per-column constants (this thread owns output channel d for 8 rows)
  const int d    = w*16 + col;
  const float br_  = b_ih[d]       + b_hh[d];
  const float bz_  = b_ih[256 + d] + b_hh[256 + d];
  const float bin_ = b_ih[512 + d];
  const float bhn_ = b_hh[512 + d];
  const float wo_  = w_out[d];

  // weight fragment flat offsets (short8 units): frag(tn,tk) = fw[tn*512 + tk*64 + lane]
  const int wq0 = (w     )*512 + lane;   // gate r
  const int wq1 = (16 + w)*512 + lane;   // gate z
  const int wq2 = (32 + w)*512 + lane;   // gate n

  // h0 = user_embs[b, clip(length[b]-1,0)]; identical for all 32 rows
  int idx = length[b] - 1; if (idx < 0) idx = 0;
  const float u0 = user[((size_t)b*SS + idx)*DD + d];
  float h[2][4];
  #pragma unroll
  for (int mt = 0; mt < 2; ++mt)
    #pragma unroll
    for (int reg = 0; reg < 4; ++reg)
      h[mt][reg] = u0;

  // write h0 into hfrag[0] (A-fragment layout), owner-thread scatter
  const int tkk = d >> 5;
  const int slb = ((d >> 3) & 3) * 16;
  const int dj  = d & 7;
  {
    unsigned short hb = f2bf(u0);
    #pragma unroll
    for (int mt = 0; mt < 2; ++mt)
      #pragma unroll
      for (int reg = 0; reg < 4; ++reg)
        hfrag[0][((mt*8 + tkk)*64 + slb + q*4 + reg)*8 + dj] = hb;
  }

  // cooperative x-tile load: thread covers row = tid>>5, 8 d's at (tid&31)*8
  const int xrow = tid >> 5;        // 0..31
  const int xo   = tid & 31;        // which 8-wide d chunk
  const int xmt  = xrow >> 4;
  const int xtk  = xo >> 2;
  const int xsl  = (xo & 3)*16 + (xrow & 15);
  {
    const float4* p = (const float4*)(item + ((size_t)(nb + xrow)*KK + 0)*DD + xo*8);
    float4 a0 = p[0], a1 = p[1];
    unsigned short t[8];
    t[0]=f2bf(a0.x); t[1]=f2bf(a0.y); t[2]=f2bf(a0.z); t[3]=f2bf(a0.w);
    t[4]=f2bf(a1.x); t[5]=f2bf(a1.y); t[6]=f2bf(a1.z); t[7]=f2bf(a1.w);
    *(short8*)&xfrag[0][((xmt*8 + xtk)*64 + xsl)*8] = *(short8*)t;
  }
  __syncthreads();

  const float bout = b_out[0];

#define MFMA16(A,Bv,C) __builtin_amdgcn_mfma_f32_16x16x32_bf16(A,Bv,C,0,0,0)

  for (int k = 0; k < KK; ++k){
    const int cb  = k & 1;
    const int nbf = cb ^ 1;

    // accumulators: [mt][kind]  kind: 0=r 1=z 2=i_n 3=h_n
    f32x4 acc[2][4];
    #pragma unroll
    for (int mt = 0; mt < 2; ++mt)
      #pragma unroll
      for (int kd = 0; kd < 4; ++kd){
        f32x4 z4 = {0.f, 0.f, 0.f, 0.f};
        acc[mt][kd] = z4;
      }

    // next x tile issued up-front: HBM/L3 latency hides under the whole MFMA phase
    float4 xn0, xn1;
    if (k < KK-1){
      const float4* p = (const float4*)(item + ((size_t)(nb + xrow)*KK + (k+1))*DD + xo*8);
      xn0 = p[0]; xn1 = p[1];
    }

    // tk loop: unroll-4 lets the compiler pipeline next-iteration weight loads
    // under current MFMAs within its register budget (no forced liveness).
    #pragma unroll 4
    for (int tk = 0; tk < 8; ++tk){
      const int tkv = (tk + sk) & 7;
      const int o_  = tkv * 64;
      short8 w1r = fw1[wq0+o_], w1z = fw1[wq1+o_], w1n = fw1[wq2+o_];
      short8 whr = fwh[wq0+o_], whz = fwh[wq1+o_], whn = fwh[wq2+o_];
      short8 ax0 = *(const short8*)&xfrag[cb][((    tkv)*64 + lane)*8];
      short8 ax1 = *(const short8*)&xfrag[cb][((8 + tkv)*64 + lane)*8];
      short8 ah0 = *(const short8*)&hfrag[cb][((    tkv)*64 + lane)*8];
      short8 ah1 = *(const short8*)&hfrag[cb][((8 + tkv)*64 + lane)*8];
      __builtin_amdgcn_s_setprio(1);
      acc[0][0] = MFMA16(ax0, w1r, acc[0][0]);
      acc[0][0] = MFMA16(ah0, whr, acc[0][0]);
      acc[0][1] = MFMA16(ax0, w1z, acc[0][1]);
      acc[0][1] = MFMA16(ah0, whz, acc[0][1]);
      acc[0][2] = MFMA16(ax0, w1n, acc[0][2]);
      acc[0][3] = MFMA16(ah0, whn, acc[0][3]);
      acc[1][0] = MFMA16(ax1, w1r, acc[1][0]);
      acc[1][0] = MFMA16(ah1, whr, acc[1][0]);
      acc[1][1] = MFMA16(ax1, w1z, acc[1][1]);
      acc[1][1] = MFMA16(ah1, whz, acc[1][1]);
      acc[1][2] = MFMA16(ax1, w1n, acc[1][2]);
      acc[1][3] = MFMA16(ah1, whn, acc[1][3]);
      __builtin_amdgcn_s_setprio(0);
    }

    // gates — entirely in-register (v_rcp + v_med3; verified same absmax)
    float ypl[2][4];
    #pragma unroll
    for (int mt = 0; mt < 2; ++mt)
      #pragma unroll
      for (int reg = 0; reg < 4; ++reg){
        float rp = acc[mt][0][reg] + br_;
        float zp = acc[mt][1][reg] + bz_;
        float r  = __builtin_amdgcn_rcpf(1.f + __expf(-rp));
        float z  = __builtin_amdgcn_rcpf(1.f + __expf(-zp));
        float np = acc[mt][2][reg] + bin_ + r*(acc[mt][3][reg] + bhn_);
        np = __builtin_amdgcn_fmed3f(np, -30.f, 30.f);
        float e  = __expf(2.f*np);
        float n  = 1.f - 2.f*__builtin_amdgcn_rcpf(e + 1.f);   // tanh(np)
        float hv = (1.f - z)*n + z*h[mt][reg];
        h[mt][reg] = hv;
        ypl[mt][reg] = hv * wo_;
      }

    // y partial: reduce across the 16 cols of this wave's group
    #pragma unroll
    for (int mt = 0; mt < 2; ++mt)
      #pragma unroll
      for (int reg = 0; reg < 4; ++reg){
        float p = ypl[mt][reg];
        p += __shfl_xor(p, 1);
        p += __shfl_xor(p, 2);
        p += __shfl_xor(p, 4);
        p += __shfl_xor(p, 8);
        if (col == 0) yp[k % 3][w][mt][q][reg] = p;
      }

    // write h' (bf16) into hfrag[nbf] for next step
    #pragma unroll
    for (int mt = 0; mt < 2; ++mt)
      #pragma unroll
      for (int reg = 0; reg < 4; ++reg)
        hfrag[nbf][((mt*8 + tkk)*64 + slb + q*4 + reg)*8 + dj] = f2bf(h[mt][reg]);

    // write next x tile into xfrag[nbf]
    if (k < KK-1){
      unsigned short t[8];
      t[0]=f2bf(xn0.x); t[1]=f2bf(xn0.y); t[2]=f2bf(xn0.z); t[3]=f2bf(xn0.w);
      t[4]=f2bf(xn1.x); t[5]=f2bf(xn1.y); t[6]=f2bf(xn1.z); t[7]=f2bf(xn1.w);
      *(short8*)&xfrag[nbf][((xmt*8 + xtk)*64 + xsl)*8] = *(short8*)t;
    }

    // finalize y for step k-1 (yp[(k-1)%3] stable since previous barrier;
    // concurrent writes go to yp[k%3] which is a different buffer)
    if (k > 0 && tid < 32){
      float s = bout;
      #pragma unroll
      for (int ww = 0; ww < 16; ++ww)
        s += yp[(k-1) % 3][ww][tid >> 4][(tid >> 2) & 3][tid & 3];
      out[(size_t)(nb + tid)*KK + (k-1)] = s;
    }

    __syncthreads();   // single barrier per step
  }

  // finalize y for the last step
  if (tid < 32){
    float s = bout;
    #pragma unroll
    for (int ww = 0; ww < 16; ++ww)
      s += yp[(KK-1) % 3][ww][tid >> 4][(tid >> 2) & 3][tid & 3];
    out[(size_t)(nb + tid)*KK + (KK-1)] = s;
  }
}

extern "C" void kernel_launch(void* const* d_in, const int* in_sizes, int n_in,
                              void* d_out, int out_size, void* d_ws, size_t ws_size,
                              hipStream_t stream) {
  const float* item   = (const float*)d_in[0];
  const float* user   = (const float*)d_in[1];
  const float* W_ih   = (const float*)d_in[2];
  const float* W_hh   = (const float*)d_in[3];
  const float* b_ih   = (const float*)d_in[4];
  const float* b_hh   = (const float*)d_in[5];
  const float* w_out  = (const float*)d_in[6];
  const float* b_out  = (const float*)d_in[7];
  const int*   length = (const int*)d_in[8];
  unsigned short* ws  = (unsigned short*)d_ws;   // needs 768 KB
  float* out = (float*)d_out;

  hipLaunchKernelGGL(prep_weights, dim3((2*FRAG_ELEMS)/256), dim3(256), 0, stream,
                     W_ih, W_hh, ws);
  hipLaunchKernelGGL(gru_main, dim3(NBLK), dim3(NT), 0, stream,
                     item, user, b_ih, b_hh, w_out, b_out, length, ws, out);
}